// Round 5
// baseline (587.386 us; speedup 1.0000x reference)
//
#include <hip/hip_runtime.h>
#include <math.h>

// ---------------------------------------------------------------------------
// GCN (2->64->32) + edge MLP (65->16->1), N=100k, E=1.6M.
// R5: k_edge was latency-bound at 41% occupancy (grid-limited, 1024 blocks);
//     -> 2048 blocks (+launch_bounds to pin 64 VGPR / 8 waves per SIMD).
//     Revert counter padding (12.8MB padded counters = L2-capacity loss per
//     atomic); compact 400KB counters are L2-resident. Keep windowed fill.
// ---------------------------------------------------------------------------

__global__ void k_count(const int* __restrict__ col, int* __restrict__ deg, int E) {
    int stride = gridDim.x * blockDim.x;
    for (int e = blockIdx.x * blockDim.x + threadIdx.x; e < E; e += stride)
        atomicAdd(deg + col[e], 1);
}

// per-block exclusive scan of deg -> start, block totals -> bsum
__global__ void k_scan1(const int* __restrict__ deg, int* __restrict__ start,
                        int* __restrict__ bsum, int N) {
    __shared__ int sd[256];
    int t = threadIdx.x;
    int n = blockIdx.x * 256 + t;
    int d = (n < N) ? deg[n] : 0;
    sd[t] = d;
    __syncthreads();
    for (int off = 1; off < 256; off <<= 1) {
        int tv = (t >= off) ? sd[t - off] : 0;
        __syncthreads();
        sd[t] += tv;
        __syncthreads();
    }
    if (n < N) start[n] = sd[t] - d;
    if (t == 255) bsum[blockIdx.x] = sd[255];
}

__global__ void k_scan2(int* __restrict__ bsum, int nb) {
    __shared__ int sd[512];
    int t = threadIdx.x;
    int d = (t < nb) ? bsum[t] : 0;
    sd[t] = d;
    __syncthreads();
    for (int off = 1; off < 512; off <<= 1) {
        int tv = (t >= off) ? sd[t - off] : 0;
        __syncthreads();
        sd[t] += tv;
        __syncthreads();
    }
    if (t < nb) bsum[t] = sd[t] - d;
}

// finalize start, init cursor, dinv, xs
__global__ void k_scan3(int* __restrict__ start, const int* __restrict__ bsum,
                        int* __restrict__ cursor, const int* __restrict__ deg,
                        const float* __restrict__ x, float* __restrict__ dinv,
                        float* __restrict__ xs, int N) {
    int n = blockIdx.x * 256 + threadIdx.x;
    if (n >= N) return;
    int s = start[n] + bsum[blockIdx.x];
    start[n] = s;
    cursor[n] = s;
    float di = rsqrtf((float)deg[n] + 1.0f);
    dinv[n] = di;
    xs[2 * n] = x[2 * n] * di;
    xs[2 * n + 1] = x[2 * n + 1] * di;
}

// phase-windowed fill: phase ph handles cols in [ph<<wshift, (ph+1)<<wshift)
__global__ void k_fill(const int* __restrict__ row, const int* __restrict__ col,
                       int* __restrict__ cursor, int* __restrict__ srcidx,
                       int E, int wshift, int nph) {
    int stride = gridDim.x * blockDim.x;
    int tid0 = blockIdx.x * blockDim.x + threadIdx.x;
    for (int ph = 0; ph < nph; ++ph) {
        for (int e = tid0; e < E; e += stride) {
            int c = col[e];
            if ((c >> wshift) == ph) {
                int p = atomicAdd(cursor + c, 1);
                srcidx[p] = row[e];
            }
        }
    }
}

// per node: agg xs over in-edges (+self), *dinv, W1+b1, relu, W2, *dinv -> hs2
__global__ void k_l1l2(const int* __restrict__ start, const int* __restrict__ deg,
                       const int* __restrict__ srcidx,
                       const float* __restrict__ xs, const float* __restrict__ dinv,
                       const float* __restrict__ W1, const float* __restrict__ b1,
                       const float* __restrict__ W2,
                       float* __restrict__ hs2, int N) {
    __shared__ float sW1[128], sb1[64], sW2[2048];
    for (int i = threadIdx.x; i < 128;  i += blockDim.x) sW1[i] = W1[i];
    for (int i = threadIdx.x; i < 64;   i += blockDim.x) sb1[i] = b1[i];
    for (int i = threadIdx.x; i < 2048; i += blockDim.x) sW2[i] = W2[i];
    __syncthreads();
    int n = blockIdx.x * 256 + threadIdx.x;
    if (n >= N) return;
    int s = start[n], cnt = deg[n];
    float a0 = xs[2 * n], a1 = xs[2 * n + 1];  // self-loop term
    for (int k = 0; k < cnt; ++k) {
        int r = srcidx[s + k];
        a0 += xs[2 * r];
        a1 += xs[2 * r + 1];
    }
    float di = dinv[n];
    a0 *= di; a1 *= di;
    float acc[32];
#pragma unroll
    for (int j = 0; j < 32; ++j) acc[j] = 0.0f;
    for (int k = 0; k < 64; ++k) {
        float h = fmaxf(fmaf(a0, sW1[k], fmaf(a1, sW1[64 + k], sb1[k])), 0.0f);
#pragma unroll
        for (int j = 0; j < 32; ++j) acc[j] = fmaf(h, sW2[k * 32 + j], acc[j]);
    }
    float4* op = (float4*)(hs2 + (size_t)n * 32);
#pragma unroll
    for (int q = 0; q < 8; ++q) {
        float4 t;
        t.x = acc[4 * q] * di; t.y = acc[4 * q + 1] * di;
        t.z = acc[4 * q + 2] * di; t.w = acc[4 * q + 3] * di;
        op[q] = t;
    }
}

// 32 lanes per node: gather-sum hs2 rows -> h2 = relu(sum*dinv+b2) -> LDS,
// then u = h2@A, v = h2@B  (A/B = mW1 rows 0..31 / 32..63)
__global__ void k_agg2uv(const int* __restrict__ start, const int* __restrict__ deg,
                         const int* __restrict__ srcidx,
                         const float* __restrict__ hs2, const float* __restrict__ dinv,
                         const float* __restrict__ b2, const float* __restrict__ mW1,
                         float* __restrict__ u, float* __restrict__ v, int N) {
    __shared__ float sA[512], sB[512], sb2[32];
    __shared__ float h2s[8][32];
    for (int i = threadIdx.x; i < 512; i += 256) { sA[i] = mW1[i]; sB[i] = mW1[512 + i]; }
    if (threadIdx.x < 32) sb2[threadIdx.x] = b2[threadIdx.x];
    __syncthreads();
    int g  = threadIdx.x >> 5;
    int ch = threadIdx.x & 31;
    int n  = blockIdx.x * 8 + g;
    if (n < N) {
        int s = start[n], cnt = deg[n];
        float acc = hs2[(size_t)n * 32 + ch];     // self loop
        for (int k = 0; k < cnt; ++k) {
            int r = srcidx[s + k];
            acc += hs2[(size_t)r * 32 + ch];
        }
        h2s[g][ch] = fmaxf(fmaf(acc, dinv[n], sb2[ch]), 0.0f);
    }
    __syncthreads();
    if (n >= N) return;
    const float* M = (ch < 16) ? sA : sB;
    int i = ch & 15;
    float s0 = 0.0f;
#pragma unroll
    for (int j = 0; j < 32; ++j) s0 = fmaf(h2s[g][j], M[j * 16 + i], s0);
    if (ch < 16) u[(size_t)n * 16 + i] = s0;
    else         v[(size_t)n * 16 + i] = s0;
}

__global__ __launch_bounds__(256, 8)
void k_edge(const int* __restrict__ row, const int* __restrict__ col,
            const float* __restrict__ ea,
            const float* __restrict__ u, const float* __restrict__ v,
            const float* __restrict__ mW1, const float* __restrict__ mb1,
            const float* __restrict__ mW2, const float* __restrict__ mb2,
            float* __restrict__ out, int E) {
    __shared__ float sC[16], sb1[16], sW2v[16], sb2s;
    if (threadIdx.x < 16) {
        sC[threadIdx.x]   = mW1[64 * 16 + threadIdx.x];
        sb1[threadIdx.x]  = mb1[threadIdx.x];
        sW2v[threadIdx.x] = mW2[threadIdx.x];
    }
    if (threadIdx.x == 0) sb2s = mb2[0];
    __syncthreads();
    int stride = gridDim.x * blockDim.x;
    for (int e = blockIdx.x * blockDim.x + threadIdx.x; e < E; e += stride) {
        int r = row[e], c = col[e];
        float a = ea[e];
        const float4* up = (const float4*)(u + (size_t)r * 16);
        const float4* vp = (const float4*)(v + (size_t)c * 16);
        float s = sb2s;
#pragma unroll
        for (int q = 0; q < 4; ++q) {
            float4 uu = up[q];
            float4 vv = vp[q];
            float h;
            h = fmaxf(uu.x + vv.x + fmaf(a, sC[4 * q + 0], sb1[4 * q + 0]), 0.0f);
            s = fmaf(h, sW2v[4 * q + 0], s);
            h = fmaxf(uu.y + vv.y + fmaf(a, sC[4 * q + 1], sb1[4 * q + 1]), 0.0f);
            s = fmaf(h, sW2v[4 * q + 1], s);
            h = fmaxf(uu.z + vv.z + fmaf(a, sC[4 * q + 2], sb1[4 * q + 2]), 0.0f);
            s = fmaf(h, sW2v[4 * q + 2], s);
            h = fmaxf(uu.w + vv.w + fmaf(a, sC[4 * q + 3], sb1[4 * q + 3]), 0.0f);
            s = fmaf(h, sW2v[4 * q + 3], s);
        }
        out[e] = 1.0f / (1.0f + expf(-s));
    }
}

extern "C" void kernel_launch(void* const* d_in, const int* in_sizes, int n_in,
                              void* d_out, int out_size, void* d_ws, size_t ws_size,
                              hipStream_t stream) {
    const float* x   = (const float*)d_in[0];
    const int*   ei  = (const int*)d_in[1];
    const float* ea  = (const float*)d_in[2];
    const float* W1  = (const float*)d_in[4];
    const float* b1  = (const float*)d_in[5];
    const float* W2  = (const float*)d_in[6];
    const float* b2  = (const float*)d_in[7];
    const float* mW1 = (const float*)d_in[8];
    const float* mb1 = (const float*)d_in[9];
    const float* mW2 = (const float*)d_in[10];
    const float* mb2 = (const float*)d_in[11];
    float* out = (float*)d_out;

    int N = in_sizes[0] / 2;
    int E = in_sizes[2];
    const int* row = ei;
    const int* col = ei + E;

    // phase window: ~8 phases over the node range
    int clog = 0; while ((1u << clog) < (unsigned)N) ++clog;
    int wshift = clog > 3 ? clog - 3 : 0;
    int nph = ((N - 1) >> wshift) + 1;

    int* deg    = (int*)d_ws;            // N
    int* start  = deg + N;               // N
    int* cursor = start + N;             // N
    int* bsum   = cursor + N;            // 1024
    int* srcidx = bsum + 1024;           // E
    float* dinv = (float*)(srcidx + E);  // N
    float* xs   = dinv + (size_t)N;      // 2N
    float* hs2  = xs + (size_t)2 * N;    // 32N
    float* u    = hs2 + (size_t)32 * N;  // 16N
    float* v    = u + (size_t)16 * N;    // 16N

    int nb_n = (N + 255) / 256;

    hipMemsetAsync(deg, 0, (size_t)N * sizeof(int), stream);
    k_count<<<2048, 256, 0, stream>>>(col, deg, E);
    k_scan1<<<nb_n, 256, 0, stream>>>(deg, start, bsum, N);
    k_scan2<<<1, 512, 0, stream>>>(bsum, nb_n);
    k_scan3<<<nb_n, 256, 0, stream>>>(start, bsum, cursor, deg, x, dinv, xs, N);
    k_fill <<<2048, 256, 0, stream>>>(row, col, cursor, srcidx, E, wshift, nph);
    k_l1l2 <<<nb_n, 256, 0, stream>>>(start, deg, srcidx, xs, dinv, W1, b1, W2, hs2, N);
    k_agg2uv<<<(N + 7) / 8, 256, 0, stream>>>(start, deg, srcidx, hs2, dinv, b2, mW1, u, v, N);
    k_edge <<<2048, 256, 0, stream>>>(row, col, ea, u, v, mW1, mb1, mW2, mb2, out, E);
}

// Round 7
// 479.793 us; speedup vs baseline: 1.2242x; 1.2242x over previous
//
#include <hip/hip_runtime.h>
#include <hip/hip_fp16.h>
#include <math.h>

// ---------------------------------------------------------------------------
// GCN (2->64->32) + edge MLP (65->16->1), N=100k, E=1.6M.
// R6 (resubmit; GPU was unavailable):
//     (a) revert launch_bounds (R5: forced 32 VGPR -> scratch spills, WRITE
//     94->315MB). Keep 2048-block grids for occupancy.
//     (b) fp16 gather tables: u/v (6.4MB f32 -> 3.2MB each) and hs2
//     (12.8 -> 6.4MB) now ~fit per-XCD 4MB L2; random-gather FETCH collapses
//     (was 0% L2 hit, 405MB at L3 BW). Arithmetic stays f32.
// ---------------------------------------------------------------------------

__global__ void k_count(const int* __restrict__ col, int* __restrict__ deg, int E) {
    int stride = gridDim.x * blockDim.x;
    for (int e = blockIdx.x * blockDim.x + threadIdx.x; e < E; e += stride)
        atomicAdd(deg + col[e], 1);
}

__global__ void k_scan1(const int* __restrict__ deg, int* __restrict__ start,
                        int* __restrict__ bsum, int N) {
    __shared__ int sd[256];
    int t = threadIdx.x;
    int n = blockIdx.x * 256 + t;
    int d = (n < N) ? deg[n] : 0;
    sd[t] = d;
    __syncthreads();
    for (int off = 1; off < 256; off <<= 1) {
        int tv = (t >= off) ? sd[t - off] : 0;
        __syncthreads();
        sd[t] += tv;
        __syncthreads();
    }
    if (n < N) start[n] = sd[t] - d;
    if (t == 255) bsum[blockIdx.x] = sd[255];
}

__global__ void k_scan2(int* __restrict__ bsum, int nb) {
    __shared__ int sd[512];
    int t = threadIdx.x;
    int d = (t < nb) ? bsum[t] : 0;
    sd[t] = d;
    __syncthreads();
    for (int off = 1; off < 512; off <<= 1) {
        int tv = (t >= off) ? sd[t - off] : 0;
        __syncthreads();
        sd[t] += tv;
        __syncthreads();
    }
    if (t < nb) bsum[t] = sd[t] - d;
}

__global__ void k_scan3(int* __restrict__ start, const int* __restrict__ bsum,
                        int* __restrict__ cursor, const int* __restrict__ deg,
                        const float* __restrict__ x, float* __restrict__ dinv,
                        float* __restrict__ xs, int N) {
    int n = blockIdx.x * 256 + threadIdx.x;
    if (n >= N) return;
    int s = start[n] + bsum[blockIdx.x];
    start[n] = s;
    cursor[n] = s;
    float di = rsqrtf((float)deg[n] + 1.0f);
    dinv[n] = di;
    xs[2 * n] = x[2 * n] * di;
    xs[2 * n + 1] = x[2 * n + 1] * di;
}

// phase-windowed fill (keeps srcidx write window L2-resident)
__global__ void k_fill(const int* __restrict__ row, const int* __restrict__ col,
                       int* __restrict__ cursor, int* __restrict__ srcidx,
                       int E, int wshift, int nph) {
    int stride = gridDim.x * blockDim.x;
    int tid0 = blockIdx.x * blockDim.x + threadIdx.x;
    for (int ph = 0; ph < nph; ++ph) {
        for (int e = tid0; e < E; e += stride) {
            int c = col[e];
            if ((c >> wshift) == ph) {
                int p = atomicAdd(cursor + c, 1);
                srcidx[p] = row[e];
            }
        }
    }
}

// per node: agg xs (+self), *dinv, W1+b1, relu, W2, *dinv -> hs2h (fp16)
__global__ void k_l1l2(const int* __restrict__ start, const int* __restrict__ deg,
                       const int* __restrict__ srcidx,
                       const float* __restrict__ xs, const float* __restrict__ dinv,
                       const float* __restrict__ W1, const float* __restrict__ b1,
                       const float* __restrict__ W2,
                       __half* __restrict__ hs2h, int N) {
    __shared__ float sW1[128], sb1[64], sW2[2048];
    for (int i = threadIdx.x; i < 128;  i += blockDim.x) sW1[i] = W1[i];
    for (int i = threadIdx.x; i < 64;   i += blockDim.x) sb1[i] = b1[i];
    for (int i = threadIdx.x; i < 2048; i += blockDim.x) sW2[i] = W2[i];
    __syncthreads();
    int n = blockIdx.x * 256 + threadIdx.x;
    if (n >= N) return;
    int s = start[n], cnt = deg[n];
    float a0 = xs[2 * n], a1 = xs[2 * n + 1];
    for (int k = 0; k < cnt; ++k) {
        int r = srcidx[s + k];
        a0 += xs[2 * r];
        a1 += xs[2 * r + 1];
    }
    float di = dinv[n];
    a0 *= di; a1 *= di;
    float acc[32];
#pragma unroll
    for (int j = 0; j < 32; ++j) acc[j] = 0.0f;
    for (int k = 0; k < 64; ++k) {
        float h = fmaxf(fmaf(a0, sW1[k], fmaf(a1, sW1[64 + k], sb1[k])), 0.0f);
#pragma unroll
        for (int j = 0; j < 32; ++j) acc[j] = fmaf(h, sW2[k * 32 + j], acc[j]);
    }
    __half2 hb[16];
#pragma unroll
    for (int j = 0; j < 16; ++j)
        hb[j] = __floats2half2_rn(acc[2 * j] * di, acc[2 * j + 1] * di);
    float4* op = (float4*)(hs2h + (size_t)n * 32);
    const float4* ip = (const float4*)hb;
#pragma unroll
    for (int q = 0; q < 4; ++q) op[q] = ip[q];
}

// 32 lanes/node: gather-sum hs2h rows -> h2=relu(sum*dinv+b2) -> LDS,
// then u16 = h2@A, v16 = h2@B (fp16 outputs)
__global__ void k_agg2uv(const int* __restrict__ start, const int* __restrict__ deg,
                         const int* __restrict__ srcidx,
                         const __half* __restrict__ hs2h, const float* __restrict__ dinv,
                         const float* __restrict__ b2, const float* __restrict__ mW1,
                         __half* __restrict__ u16, __half* __restrict__ v16, int N) {
    __shared__ float sA[512], sB[512], sb2[32];
    __shared__ float h2s[8][32];
    for (int i = threadIdx.x; i < 512; i += 256) { sA[i] = mW1[i]; sB[i] = mW1[512 + i]; }
    if (threadIdx.x < 32) sb2[threadIdx.x] = b2[threadIdx.x];
    __syncthreads();
    int g  = threadIdx.x >> 5;
    int ch = threadIdx.x & 31;
    int n  = blockIdx.x * 8 + g;
    if (n < N) {
        int s = start[n], cnt = deg[n];
        float acc = __half2float(hs2h[(size_t)n * 32 + ch]);   // self loop
        for (int k = 0; k < cnt; ++k) {
            int r = srcidx[s + k];
            acc += __half2float(hs2h[(size_t)r * 32 + ch]);
        }
        h2s[g][ch] = fmaxf(fmaf(acc, dinv[n], sb2[ch]), 0.0f);
    }
    __syncthreads();
    if (n >= N) return;
    const float* M = (ch < 16) ? sA : sB;
    int i = ch & 15;
    float s0 = 0.0f;
#pragma unroll
    for (int j = 0; j < 32; ++j) s0 = fmaf(h2s[g][j], M[j * 16 + i], s0);
    if (ch < 16) u16[(size_t)n * 16 + i] = __float2half_rn(s0);
    else         v16[(size_t)n * 16 + i] = __float2half_rn(s0);
}

__device__ inline void unpack8(const float4 f, float* o) {
    const __half2* h2 = (const __half2*)&f;
#pragma unroll
    for (int i = 0; i < 4; ++i) {
        float2 t = __half22float2(h2[i]);
        o[2 * i] = t.x; o[2 * i + 1] = t.y;
    }
}

__global__ void k_edge(const int* __restrict__ row, const int* __restrict__ col,
                       const float* __restrict__ ea,
                       const __half* __restrict__ u16, const __half* __restrict__ v16,
                       const float* __restrict__ mW1, const float* __restrict__ mb1,
                       const float* __restrict__ mW2, const float* __restrict__ mb2,
                       float* __restrict__ out, int E) {
    __shared__ float sC[16], sb1[16], sW2v[16], sb2s;
    if (threadIdx.x < 16) {
        sC[threadIdx.x]   = mW1[64 * 16 + threadIdx.x];
        sb1[threadIdx.x]  = mb1[threadIdx.x];
        sW2v[threadIdx.x] = mW2[threadIdx.x];
    }
    if (threadIdx.x == 0) sb2s = mb2[0];
    __syncthreads();
    int stride = gridDim.x * blockDim.x;
    for (int e = blockIdx.x * blockDim.x + threadIdx.x; e < E; e += stride) {
        int r = row[e], c = col[e];
        float a = ea[e];
        const float4* up = (const float4*)(u16 + (size_t)r * 16);
        const float4* vp = (const float4*)(v16 + (size_t)c * 16);
        float4 u0 = up[0], u1 = up[1];
        float4 v0 = vp[0], v1 = vp[1];
        float uf[16], vf[16];
        unpack8(u0, uf); unpack8(u1, uf + 8);
        unpack8(v0, vf); unpack8(v1, vf + 8);
        float s = sb2s;
#pragma unroll
        for (int i = 0; i < 16; ++i) {
            float h = fmaxf(uf[i] + vf[i] + fmaf(a, sC[i], sb1[i]), 0.0f);
            s = fmaf(h, sW2v[i], s);
        }
        out[e] = 1.0f / (1.0f + expf(-s));
    }
}

extern "C" void kernel_launch(void* const* d_in, const int* in_sizes, int n_in,
                              void* d_out, int out_size, void* d_ws, size_t ws_size,
                              hipStream_t stream) {
    const float* x   = (const float*)d_in[0];
    const int*   ei  = (const int*)d_in[1];
    const float* ea  = (const float*)d_in[2];
    const float* W1  = (const float*)d_in[4];
    const float* b1  = (const float*)d_in[5];
    const float* W2  = (const float*)d_in[6];
    const float* b2  = (const float*)d_in[7];
    const float* mW1 = (const float*)d_in[8];
    const float* mb1 = (const float*)d_in[9];
    const float* mW2 = (const float*)d_in[10];
    const float* mb2 = (const float*)d_in[11];
    float* out = (float*)d_out;

    int N = in_sizes[0] / 2;
    int E = in_sizes[2];
    const int* row = ei;
    const int* col = ei + E;

    int clog = 0; while ((1u << clog) < (unsigned)N) ++clog;
    int wshift = clog > 3 ? clog - 3 : 0;
    int nph = ((N - 1) >> wshift) + 1;

    int* deg    = (int*)d_ws;            // N
    int* start  = deg + N;               // N
    int* cursor = start + N;             // N
    int* bsum   = cursor + N;            // 1024
    int* srcidx = bsum + 1024;           // E
    float* dinv = (float*)(srcidx + E);  // N floats
    float* xs   = dinv + (size_t)N;      // 2N floats
    __half* hs2h = (__half*)(xs + (size_t)2 * N);   // 32N halves (16N float-slots)
    __half* u16  = hs2h + (size_t)32 * N;           // 16N halves
    __half* v16  = u16 + (size_t)16 * N;            // 16N halves

    int nb_n = (N + 255) / 256;

    hipMemsetAsync(deg, 0, (size_t)N * sizeof(int), stream);
    k_count<<<2048, 256, 0, stream>>>(col, deg, E);
    k_scan1<<<nb_n, 256, 0, stream>>>(deg, start, bsum, N);
    k_scan2<<<1, 512, 0, stream>>>(bsum, nb_n);
    k_scan3<<<nb_n, 256, 0, stream>>>(start, bsum, cursor, deg, x, dinv, xs, N);
    k_fill <<<2048, 256, 0, stream>>>(row, col, cursor, srcidx, E, wshift, nph);
    k_l1l2 <<<nb_n, 256, 0, stream>>>(start, deg, srcidx, xs, dinv, W1, b1, W2, hs2h, N);
    k_agg2uv<<<(N + 7) / 8, 256, 0, stream>>>(start, deg, srcidx, hs2h, dinv, b2, mW1, u16, v16, N);
    k_edge <<<2048, 256, 0, stream>>>(row, col, ea, u16, v16, mW1, mb1, mW2, mb2, out, E);
}